// Round 1
// baseline (727.521 us; speedup 1.0000x reference)
//
#include <hip/hip_runtime.h>
#include <hip/hip_bf16.h>
#include <math.h>

#define NFEAT 128
#define NCLASS 40

// ---------------- CSR build ----------------

__global__ __launch_bounds__(256) void hist_kernel(const int* __restrict__ dst,
                                                   int* __restrict__ counts, int n_edges) {
    int e = blockIdx.x * 256 + threadIdx.x;
    if (e < n_edges) atomicAdd(&counts[dst[e]], 1);
}

// single-block chunked scan: counts (in woff) -> exclusive offsets (row_ptr and woff)
__global__ __launch_bounds__(1024) void scan_kernel(int* __restrict__ woff,
                                                    int* __restrict__ row_ptr, int n) {
    __shared__ int sd[1024];
    int t = threadIdx.x;
    int ch = (n + 1023) >> 10;
    int b = t * ch;
    int e = min(n, b + ch);
    int s = 0;
    for (int i = b; i < e; ++i) s += woff[i];
    sd[t] = s;
    __syncthreads();
    for (int off = 1; off < 1024; off <<= 1) {
        int tmp = (t >= off) ? sd[t - off] : 0;
        __syncthreads();
        sd[t] += tmp;
        __syncthreads();
    }
    int run = sd[t] - s;  // exclusive prefix of this chunk
    for (int i = b; i < e; ++i) {
        int c = woff[i];
        row_ptr[i] = run;
        woff[i] = run;
        run += c;
    }
    if (t == 1023) row_ptr[n] = sd[1023];
}

__global__ __launch_bounds__(256) void scatter_kernel(const int* __restrict__ src,
                                                      const int* __restrict__ dst,
                                                      int* __restrict__ woff,
                                                      int* __restrict__ src_sorted, int n_edges) {
    int e = blockIdx.x * 256 + threadIdx.x;
    if (e < n_edges) {
        int p = atomicAdd(&woff[dst[e]], 1);
        src_sorted[p] = src[e];
    }
}

// ---------------- aggregation: one wave per node, lane = 2 cols ----------------

__global__ __launch_bounds__(256) void agg_kernel(const float* __restrict__ xin,
                                                  const int* __restrict__ row_ptr,
                                                  const int* __restrict__ src_sorted,
                                                  float* __restrict__ agg, int n_nodes) {
    int node = blockIdx.x * 4 + (threadIdx.x >> 6);
    int lane = threadIdx.x & 63;
    if (node >= n_nodes) return;
    int jb = row_ptr[node], je = row_ptr[node + 1];
    const float2* x2 = (const float2*)xin;
    float2 a0 = {0.f, 0.f}, a1 = {0.f, 0.f};
    int j = jb;
    for (; j + 1 < je; j += 2) {
        int s0 = src_sorted[j];
        int s1 = src_sorted[j + 1];
        float2 v0 = x2[s0 * 64 + lane];
        float2 v1 = x2[s1 * 64 + lane];
        a0.x += v0.x; a0.y += v0.y;
        a1.x += v1.x; a1.y += v1.y;
    }
    if (j < je) {
        int s0 = src_sorted[j];
        float2 v0 = x2[s0 * 64 + lane];
        a0.x += v0.x; a0.y += v0.y;
    }
    float2 r;
    r.x = a0.x + a1.x;
    r.y = a0.y + a1.y;
    ((float2*)agg)[node * 64 + lane] = r;
}

// ---------------- fused GEMM (M x 128 @ 128 x 128) + bias + L2-normalize + ReLU ----------------
// block: 256 thr; tile 64 rows x 128 cols; thread = 8 rows x 4 cols.
// W staged in LDS in two 64-k halves (32 KB).

__global__ __launch_bounds__(256, 4) void gemm_norm_kernel(const float* __restrict__ A,
                                                           const float* __restrict__ W,
                                                           const float* __restrict__ bias,
                                                           float* __restrict__ out, int M) {
    __shared__ float Ws[64 * 128];  // 32 KB
    int tx = threadIdx.x & 31;
    int ty = threadIdx.x >> 5;
    int row0 = blockIdx.x * 64 + ty * 8;
    int col = tx * 4;

    const float* Ap[8];
#pragma unroll
    for (int r = 0; r < 8; ++r) {
        int row = row0 + r;
        if (row > M - 1) row = M - 1;  // clamp; stores are guarded
        Ap[r] = A + (long)row * NFEAT;
    }
    float4 acc[8];
#pragma unroll
    for (int r = 0; r < 8; ++r) acc[r] = make_float4(0.f, 0.f, 0.f, 0.f);

    for (int kb = 0; kb < 128; kb += 64) {
        __syncthreads();
        {
            const float4* Wg = (const float4*)(W + kb * NFEAT);
            float4* Ws4 = (float4*)Ws;
            for (int i = threadIdx.x; i < 64 * 32; i += 256) Ws4[i] = Wg[i];
        }
        __syncthreads();
#pragma unroll 4
        for (int k = 0; k < 64; k += 4) {
            float4 w0 = *(const float4*)&Ws[(k + 0) * NFEAT + col];
            float4 w1 = *(const float4*)&Ws[(k + 1) * NFEAT + col];
            float4 w2 = *(const float4*)&Ws[(k + 2) * NFEAT + col];
            float4 w3 = *(const float4*)&Ws[(k + 3) * NFEAT + col];
#pragma unroll
            for (int r = 0; r < 8; ++r) {
                float4 a = *(const float4*)(Ap[r] + kb + k);
                acc[r].x += a.x * w0.x; acc[r].y += a.x * w0.y; acc[r].z += a.x * w0.z; acc[r].w += a.x * w0.w;
                acc[r].x += a.y * w1.x; acc[r].y += a.y * w1.y; acc[r].z += a.y * w1.z; acc[r].w += a.y * w1.w;
                acc[r].x += a.z * w2.x; acc[r].y += a.z * w2.y; acc[r].z += a.z * w2.z; acc[r].w += a.z * w2.w;
                acc[r].x += a.w * w3.x; acc[r].y += a.w * w3.y; acc[r].z += a.w * w3.z; acc[r].w += a.w * w3.w;
            }
        }
    }

    float4 bb = *(const float4*)&bias[col];
#pragma unroll
    for (int r = 0; r < 8; ++r) {
        float4 v = acc[r];
        v.x += bb.x; v.y += bb.y; v.z += bb.z; v.w += bb.w;
        float ss = v.x * v.x + v.y * v.y + v.z * v.z + v.w * v.w;
#pragma unroll
        for (int off = 16; off >= 1; off >>= 1) ss += __shfl_xor(ss, off);  // reduce over 32 tx lanes
        float inv = 1.0f / fmaxf(sqrtf(ss), 1e-12f);
        v.x = fmaxf(v.x * inv, 0.f);
        v.y = fmaxf(v.y * inv, 0.f);
        v.z = fmaxf(v.z * inv, 0.f);
        v.w = fmaxf(v.w * inv, 0.f);
        int row = row0 + r;
        if (row < M) *(float4*)&out[(long)row * NFEAT + col] = v;
    }
}

// ---------------- classifier: logits = x4 @ Wl + bl; softmax ----------------
// one wave per node; lanes 0..39 = classes

__global__ __launch_bounds__(256) void classifier_kernel(const float* __restrict__ x4,
                                                         const float* __restrict__ Wl,
                                                         const float* __restrict__ bl,
                                                         float* __restrict__ logits,
                                                         float* __restrict__ probs, int n_nodes) {
    __shared__ float Wls[NFEAT * NCLASS];  // 20 KB
    __shared__ float rows[4][NFEAT];
    for (int i = threadIdx.x; i < NFEAT * NCLASS; i += 256) Wls[i] = Wl[i];
    int wv = threadIdx.x >> 6;
    int lane = threadIdx.x & 63;
    int node = blockIdx.x * 4 + wv;
    if (node < n_nodes) {
        ((float2*)rows[wv])[lane] = ((const float2*)x4)[node * 64 + lane];
    }
    __syncthreads();
    int c = lane < NCLASS ? lane : 0;
    float acc = bl[c];
    const float* rw = rows[wv];
#pragma unroll 8
    for (int k = 0; k < NFEAT; ++k) acc += rw[k] * Wls[k * NCLASS + c];
    float lg = acc;
    float m = (lane < NCLASS) ? lg : -INFINITY;
#pragma unroll
    for (int off = 32; off >= 1; off >>= 1) m = fmaxf(m, __shfl_xor(m, off));
    float ex = (lane < NCLASS) ? expf(lg - m) : 0.f;
    float sum = ex;
#pragma unroll
    for (int off = 32; off >= 1; off >>= 1) sum += __shfl_xor(sum, off);
    float p = ex / sum;
    if (node < n_nodes && lane < NCLASS) {
        logits[(size_t)node * NCLASS + lane] = lg;
        probs[(size_t)node * NCLASS + lane] = p;
    }
}

// ---------------- launch ----------------

extern "C" void kernel_launch(void* const* d_in, const int* in_sizes, int n_in,
                              void* d_out, int out_size, void* d_ws, size_t ws_size,
                              hipStream_t stream) {
    const float* x  = (const float*)d_in[0];
    const int*   ei = (const int*)d_in[1];
    const float* W1 = (const float*)d_in[2];
    const float* b1 = (const float*)d_in[3];
    const float* W2 = (const float*)d_in[4];
    const float* b2 = (const float*)d_in[5];
    const float* W3 = (const float*)d_in[6];
    const float* b3 = (const float*)d_in[7];
    const float* W4 = (const float*)d_in[8];
    const float* b4 = (const float*)d_in[9];
    const float* Wl = (const float*)d_in[10];
    const float* bl = (const float*)d_in[11];

    const int n_nodes = in_sizes[0] / NFEAT;  // 50000
    const int n_edges = in_sizes[1] / 2;      // 640000
    const int* src = ei;
    const int* dst = ei + n_edges;

    float* out    = (float*)d_out;
    float* logits = out;
    float* probs  = out + (size_t)n_nodes * NCLASS;
    float* x4     = out + 2 * (size_t)n_nodes * NCLASS;  // also the layer ping buffer

    // workspace layout
    char* ws = (char*)d_ws;
    size_t off = 0;
    auto wsalloc = [&](size_t bytes) -> void* {
        void* p = ws + off;
        off += (bytes + 255) & ~(size_t)255;
        return p;
    };
    float* agg      = (float*)wsalloc((size_t)n_nodes * NFEAT * sizeof(float));
    int*   row_ptr  = (int*)wsalloc(((size_t)n_nodes + 1) * sizeof(int));
    int*   woff     = (int*)wsalloc((size_t)n_nodes * sizeof(int));
    int*   src_sorted = (int*)wsalloc((size_t)n_edges * sizeof(int));

    // CSR build (dst-bucketed)
    hipMemsetAsync(woff, 0, (size_t)n_nodes * sizeof(int), stream);
    int eb = (n_edges + 255) / 256;
    hist_kernel<<<eb, 256, 0, stream>>>(dst, woff, n_edges);
    scan_kernel<<<1, 1024, 0, stream>>>(woff, row_ptr, n_nodes);
    scatter_kernel<<<eb, 256, 0, stream>>>(src, dst, woff, src_sorted, n_edges);

    int nb4 = (n_nodes + 3) / 4;
    int gb  = (n_nodes + 63) / 64;

    // layer 1: aggregate raw x, then GEMM+bias+norm+relu  (agg-first reordering)
    agg_kernel<<<nb4, 256, 0, stream>>>(x, row_ptr, src_sorted, agg, n_nodes);
    gemm_norm_kernel<<<gb, 256, 0, stream>>>(agg, W1, b1, x4, n_nodes);
    // layer 2
    agg_kernel<<<nb4, 256, 0, stream>>>(x4, row_ptr, src_sorted, agg, n_nodes);
    gemm_norm_kernel<<<gb, 256, 0, stream>>>(agg, W2, b2, x4, n_nodes);
    // layer 3
    agg_kernel<<<nb4, 256, 0, stream>>>(x4, row_ptr, src_sorted, agg, n_nodes);
    gemm_norm_kernel<<<gb, 256, 0, stream>>>(agg, W3, b3, x4, n_nodes);
    // layer 4 (writes x4 output region directly)
    agg_kernel<<<nb4, 256, 0, stream>>>(x4, row_ptr, src_sorted, agg, n_nodes);
    gemm_norm_kernel<<<gb, 256, 0, stream>>>(agg, W4, b4, x4, n_nodes);

    // classifier + softmax
    classifier_kernel<<<nb4, 256, 0, stream>>>(x4, Wl, bl, logits, probs, n_nodes);
}

// Round 2
// 608.581 us; speedup vs baseline: 1.1954x; 1.1954x over previous
//
#include <hip/hip_runtime.h>
#include <hip/hip_bf16.h>
#include <math.h>

#define NFEAT 128
#define NCLASS 40

// ---------------- CSR build ----------------

__global__ __launch_bounds__(256) void hist_kernel(const int* __restrict__ dst,
                                                   int* __restrict__ counts, int n_edges) {
    int e = blockIdx.x * 256 + threadIdx.x;
    if (e < n_edges) atomicAdd(&counts[dst[e]], 1);
}

// Phase 1: per-block (256-wide) exclusive scan of counts; block totals out.
__global__ __launch_bounds__(256) void scan1_kernel(const int* __restrict__ cnt,
                                                    int* __restrict__ excl,
                                                    int* __restrict__ bsums, int n) {
    __shared__ int sd[256];
    int t = threadIdx.x;
    int i = blockIdx.x * 256 + t;
    int v = (i < n) ? cnt[i] : 0;
    sd[t] = v;
    __syncthreads();
#pragma unroll
    for (int off = 1; off < 256; off <<= 1) {
        int tmp = (t >= off) ? sd[t - off] : 0;
        __syncthreads();
        sd[t] += tmp;
        __syncthreads();
    }
    if (i < n) excl[i] = sd[t] - v;
    if (t == 255) bsums[blockIdx.x] = sd[255];
}

// Phase 2: single block scans the (<=256) block sums in-place (exclusive),
// appends grand total at bsums[nb].
__global__ __launch_bounds__(256) void scan2_kernel(int* __restrict__ bsums, int nb) {
    __shared__ int sd[256];
    int t = threadIdx.x;
    int v = (t < nb) ? bsums[t] : 0;
    sd[t] = v;
    __syncthreads();
#pragma unroll
    for (int off = 1; off < 256; off <<= 1) {
        int tmp = (t >= off) ? sd[t - off] : 0;
        __syncthreads();
        sd[t] += tmp;
        __syncthreads();
    }
    if (t < nb) bsums[t] = sd[t] - v;
    if (t == 255) bsums[nb] = sd[255];
}

// Phase 3: add block offsets -> final row_ptr and woff (scatter cursor).
__global__ __launch_bounds__(256) void scan3_kernel(const int* __restrict__ excl,
                                                    const int* __restrict__ bsums,
                                                    int* __restrict__ row_ptr,
                                                    int* __restrict__ woff, int n, int nb) {
    int i = blockIdx.x * 256 + threadIdx.x;
    if (i < n) {
        int v = excl[i] + bsums[blockIdx.x];
        row_ptr[i] = v;
        woff[i] = v;
    }
    if (i == 0) row_ptr[n] = bsums[nb];
}

__global__ __launch_bounds__(256) void scatter_kernel(const int* __restrict__ src,
                                                      const int* __restrict__ dst,
                                                      int* __restrict__ woff,
                                                      int* __restrict__ src_sorted, int n_edges) {
    int e = blockIdx.x * 256 + threadIdx.x;
    if (e < n_edges) {
        int p = atomicAdd(&woff[dst[e]], 1);
        src_sorted[p] = src[e];
    }
}

// ---------------- aggregation ----------------
// One wave per node. Lane = (half, colgroup): half-wave h handles edges
// jb+h, jb+h+2, ...; each lane gathers a float4 (16 B) -> global_load_dwordx4,
// 4 edges (2 KB) per unrolled wave-iteration, 2 loads in flight per lane.

__global__ __launch_bounds__(256) void agg_kernel(const float* __restrict__ xin,
                                                  const int* __restrict__ row_ptr,
                                                  const int* __restrict__ src_sorted,
                                                  float* __restrict__ agg, int n_nodes) {
    int node = blockIdx.x * 4 + (threadIdx.x >> 6);
    if (node >= n_nodes) return;
    int lane = threadIdx.x & 63;
    int half = lane >> 5;
    int c = lane & 31;  // float4 column group: cols [4c, 4c+3]
    int jb = row_ptr[node], je = row_ptr[node + 1];
    const float4* x4p = (const float4*)xin;  // row stride 32 float4s

    float4 a0 = make_float4(0.f, 0.f, 0.f, 0.f);
    float4 a1 = make_float4(0.f, 0.f, 0.f, 0.f);
    int j = jb + half;
    for (; j + 2 < je; j += 4) {
        int s0 = src_sorted[j];
        int s1 = src_sorted[j + 2];
        float4 v0 = x4p[s0 * 32 + c];
        float4 v1 = x4p[s1 * 32 + c];
        a0.x += v0.x; a0.y += v0.y; a0.z += v0.z; a0.w += v0.w;
        a1.x += v1.x; a1.y += v1.y; a1.z += v1.z; a1.w += v1.w;
    }
    for (; j < je; j += 2) {
        int s0 = src_sorted[j];
        float4 v0 = x4p[s0 * 32 + c];
        a0.x += v0.x; a0.y += v0.y; a0.z += v0.z; a0.w += v0.w;
    }
    a0.x += a1.x; a0.y += a1.y; a0.z += a1.z; a0.w += a1.w;
    // fold odd half onto even half
    a0.x += __shfl_xor(a0.x, 32);
    a0.y += __shfl_xor(a0.y, 32);
    a0.z += __shfl_xor(a0.z, 32);
    a0.w += __shfl_xor(a0.w, 32);
    if (half == 0) ((float4*)agg)[node * 32 + c] = a0;
}

// ---------------- fused GEMM (M x 128 @ 128 x 128) + bias + L2-normalize + ReLU ----------------

__global__ __launch_bounds__(256, 4) void gemm_norm_kernel(const float* __restrict__ A,
                                                           const float* __restrict__ W,
                                                           const float* __restrict__ bias,
                                                           float* __restrict__ out, int M) {
    __shared__ float Ws[64 * 128];  // 32 KB
    int tx = threadIdx.x & 31;
    int ty = threadIdx.x >> 5;
    int row0 = blockIdx.x * 64 + ty * 8;
    int col = tx * 4;

    const float* Ap[8];
#pragma unroll
    for (int r = 0; r < 8; ++r) {
        int row = row0 + r;
        if (row > M - 1) row = M - 1;  // clamp; stores are guarded
        Ap[r] = A + (long)row * NFEAT;
    }
    float4 acc[8];
#pragma unroll
    for (int r = 0; r < 8; ++r) acc[r] = make_float4(0.f, 0.f, 0.f, 0.f);

    for (int kb = 0; kb < 128; kb += 64) {
        __syncthreads();
        {
            const float4* Wg = (const float4*)(W + kb * NFEAT);
            float4* Ws4 = (float4*)Ws;
            for (int i = threadIdx.x; i < 64 * 32; i += 256) Ws4[i] = Wg[i];
        }
        __syncthreads();
#pragma unroll 4
        for (int k = 0; k < 64; k += 4) {
            float4 w0 = *(const float4*)&Ws[(k + 0) * NFEAT + col];
            float4 w1 = *(const float4*)&Ws[(k + 1) * NFEAT + col];
            float4 w2 = *(const float4*)&Ws[(k + 2) * NFEAT + col];
            float4 w3 = *(const float4*)&Ws[(k + 3) * NFEAT + col];
#pragma unroll
            for (int r = 0; r < 8; ++r) {
                float4 a = *(const float4*)(Ap[r] + kb + k);
                acc[r].x += a.x * w0.x; acc[r].y += a.x * w0.y; acc[r].z += a.x * w0.z; acc[r].w += a.x * w0.w;
                acc[r].x += a.y * w1.x; acc[r].y += a.y * w1.y; acc[r].z += a.y * w1.z; acc[r].w += a.y * w1.w;
                acc[r].x += a.z * w2.x; acc[r].y += a.z * w2.y; acc[r].z += a.z * w2.z; acc[r].w += a.z * w2.w;
                acc[r].x += a.w * w3.x; acc[r].y += a.w * w3.y; acc[r].z += a.w * w3.z; acc[r].w += a.w * w3.w;
            }
        }
    }

    float4 bb = *(const float4*)&bias[col];
#pragma unroll
    for (int r = 0; r < 8; ++r) {
        float4 v = acc[r];
        v.x += bb.x; v.y += bb.y; v.z += bb.z; v.w += bb.w;
        float ss = v.x * v.x + v.y * v.y + v.z * v.z + v.w * v.w;
#pragma unroll
        for (int off = 16; off >= 1; off >>= 1) ss += __shfl_xor(ss, off);  // reduce over 32 tx lanes
        float inv = 1.0f / fmaxf(sqrtf(ss), 1e-12f);
        v.x = fmaxf(v.x * inv, 0.f);
        v.y = fmaxf(v.y * inv, 0.f);
        v.z = fmaxf(v.z * inv, 0.f);
        v.w = fmaxf(v.w * inv, 0.f);
        int row = row0 + r;
        if (row < M) *(float4*)&out[(long)row * NFEAT + col] = v;
    }
}

// ---------------- classifier: logits = x4 @ Wl + bl; softmax ----------------

__global__ __launch_bounds__(256) void classifier_kernel(const float* __restrict__ x4,
                                                         const float* __restrict__ Wl,
                                                         const float* __restrict__ bl,
                                                         float* __restrict__ logits,
                                                         float* __restrict__ probs, int n_nodes) {
    __shared__ float Wls[NFEAT * NCLASS];  // 20 KB
    __shared__ float rows[4][NFEAT];
    for (int i = threadIdx.x; i < NFEAT * NCLASS; i += 256) Wls[i] = Wl[i];
    int wv = threadIdx.x >> 6;
    int lane = threadIdx.x & 63;
    int node = blockIdx.x * 4 + wv;
    if (node < n_nodes) {
        ((float2*)rows[wv])[lane] = ((const float2*)x4)[node * 64 + lane];
    }
    __syncthreads();
    int c = lane < NCLASS ? lane : 0;
    float acc = bl[c];
    const float* rw = rows[wv];
#pragma unroll 8
    for (int k = 0; k < NFEAT; ++k) acc += rw[k] * Wls[k * NCLASS + c];
    float lg = acc;
    float m = (lane < NCLASS) ? lg : -INFINITY;
#pragma unroll
    for (int off = 32; off >= 1; off >>= 1) m = fmaxf(m, __shfl_xor(m, off));
    float ex = (lane < NCLASS) ? expf(lg - m) : 0.f;
    float sum = ex;
#pragma unroll
    for (int off = 32; off >= 1; off >>= 1) sum += __shfl_xor(sum, off);
    float p = ex / sum;
    if (node < n_nodes && lane < NCLASS) {
        logits[(size_t)node * NCLASS + lane] = lg;
        probs[(size_t)node * NCLASS + lane] = p;
    }
}

// ---------------- launch ----------------

extern "C" void kernel_launch(void* const* d_in, const int* in_sizes, int n_in,
                              void* d_out, int out_size, void* d_ws, size_t ws_size,
                              hipStream_t stream) {
    const float* x  = (const float*)d_in[0];
    const int*   ei = (const int*)d_in[1];
    const float* W1 = (const float*)d_in[2];
    const float* b1 = (const float*)d_in[3];
    const float* W2 = (const float*)d_in[4];
    const float* b2 = (const float*)d_in[5];
    const float* W3 = (const float*)d_in[6];
    const float* b3 = (const float*)d_in[7];
    const float* W4 = (const float*)d_in[8];
    const float* b4 = (const float*)d_in[9];
    const float* Wl = (const float*)d_in[10];
    const float* bl = (const float*)d_in[11];

    const int n_nodes = in_sizes[0] / NFEAT;  // 50000
    const int n_edges = in_sizes[1] / 2;      // 640000
    const int* src = ei;
    const int* dst = ei + n_edges;

    float* out    = (float*)d_out;
    float* logits = out;
    float* probs  = out + (size_t)n_nodes * NCLASS;
    float* x4     = out + 2 * (size_t)n_nodes * NCLASS;  // also the layer ping buffer

    // workspace layout
    char* ws = (char*)d_ws;
    size_t off = 0;
    auto wsalloc = [&](size_t bytes) -> void* {
        void* p = ws + off;
        off += (bytes + 255) & ~(size_t)255;
        return p;
    };
    float* agg        = (float*)wsalloc((size_t)n_nodes * NFEAT * sizeof(float));
    int*   row_ptr    = (int*)wsalloc(((size_t)n_nodes + 1) * sizeof(int));
    int*   woff       = (int*)wsalloc((size_t)n_nodes * sizeof(int));
    int*   cnt        = (int*)wsalloc((size_t)n_nodes * sizeof(int));
    int*   src_sorted = (int*)wsalloc((size_t)n_edges * sizeof(int));
    int    nb         = (n_nodes + 255) / 256;
    int*   bsums      = (int*)wsalloc(((size_t)nb + 1) * sizeof(int));

    // CSR build (dst-bucketed)
    hipMemsetAsync(cnt, 0, (size_t)n_nodes * sizeof(int), stream);
    int eb = (n_edges + 255) / 256;
    hist_kernel<<<eb, 256, 0, stream>>>(dst, cnt, n_edges);
    scan1_kernel<<<nb, 256, 0, stream>>>(cnt, row_ptr /*excl temp*/, bsums, n_nodes);
    scan2_kernel<<<1, 256, 0, stream>>>(bsums, nb);
    scan3_kernel<<<nb, 256, 0, stream>>>(row_ptr, bsums, row_ptr, woff, n_nodes, nb);
    scatter_kernel<<<eb, 256, 0, stream>>>(src, dst, woff, src_sorted, n_edges);

    int nb4 = (n_nodes + 3) / 4;
    int gb  = (n_nodes + 63) / 64;

    // layer 1 (agg-first reordering: segment_sum commutes with @W)
    agg_kernel<<<nb4, 256, 0, stream>>>(x, row_ptr, src_sorted, agg, n_nodes);
    gemm_norm_kernel<<<gb, 256, 0, stream>>>(agg, W1, b1, x4, n_nodes);
    // layer 2
    agg_kernel<<<nb4, 256, 0, stream>>>(x4, row_ptr, src_sorted, agg, n_nodes);
    gemm_norm_kernel<<<gb, 256, 0, stream>>>(agg, W2, b2, x4, n_nodes);
    // layer 3
    agg_kernel<<<nb4, 256, 0, stream>>>(x4, row_ptr, src_sorted, agg, n_nodes);
    gemm_norm_kernel<<<gb, 256, 0, stream>>>(agg, W3, b3, x4, n_nodes);
    // layer 4 (writes x4 output region directly)
    agg_kernel<<<nb4, 256, 0, stream>>>(x4, row_ptr, src_sorted, agg, n_nodes);
    gemm_norm_kernel<<<gb, 256, 0, stream>>>(agg, W4, b4, x4, n_nodes);

    // classifier + softmax
    classifier_kernel<<<nb4, 256, 0, stream>>>(x4, Wl, bl, logits, probs, n_nodes);
}

// Round 3
// 517.325 us; speedup vs baseline: 1.4063x; 1.1764x over previous
//
#include <hip/hip_runtime.h>
#include <hip/hip_bf16.h>
#include <math.h>

#define NFEAT 128
#define NCLASS 40

// ---------------- CSR build ----------------

__global__ __launch_bounds__(256) void hist_kernel(const int* __restrict__ dst,
                                                   int* __restrict__ counts, int n_edges) {
    int e = blockIdx.x * 256 + threadIdx.x;
    if (e < n_edges) atomicAdd(&counts[dst[e]], 1);
}

// Phase 1: per-block (256-wide) exclusive scan of counts; block totals out.
__global__ __launch_bounds__(256) void scan1_kernel(const int* __restrict__ cnt,
                                                    int* __restrict__ excl,
                                                    int* __restrict__ bsums, int n) {
    __shared__ int sd[256];
    int t = threadIdx.x;
    int i = blockIdx.x * 256 + t;
    int v = (i < n) ? cnt[i] : 0;
    sd[t] = v;
    __syncthreads();
#pragma unroll
    for (int off = 1; off < 256; off <<= 1) {
        int tmp = (t >= off) ? sd[t - off] : 0;
        __syncthreads();
        sd[t] += tmp;
        __syncthreads();
    }
    if (i < n) excl[i] = sd[t] - v;
    if (t == 255) bsums[blockIdx.x] = sd[255];
}

// Phase 2: single block scans the (<=256) block sums in-place (exclusive),
// appends grand total at bsums[nb].
__global__ __launch_bounds__(256) void scan2_kernel(int* __restrict__ bsums, int nb) {
    __shared__ int sd[256];
    int t = threadIdx.x;
    int v = (t < nb) ? bsums[t] : 0;
    sd[t] = v;
    __syncthreads();
#pragma unroll
    for (int off = 1; off < 256; off <<= 1) {
        int tmp = (t >= off) ? sd[t - off] : 0;
        __syncthreads();
        sd[t] += tmp;
        __syncthreads();
    }
    if (t < nb) bsums[t] = sd[t] - v;
    if (t == 255) bsums[nb] = sd[255];
}

// Phase 3: add block offsets -> final row_ptr and woff (scatter cursor).
__global__ __launch_bounds__(256) void scan3_kernel(const int* __restrict__ excl,
                                                    const int* __restrict__ bsums,
                                                    int* __restrict__ row_ptr,
                                                    int* __restrict__ woff, int n, int nb) {
    int i = blockIdx.x * 256 + threadIdx.x;
    if (i < n) {
        int v = excl[i] + bsums[blockIdx.x];
        row_ptr[i] = v;
        woff[i] = v;
    }
    if (i == 0) row_ptr[n] = bsums[nb];
}

__global__ __launch_bounds__(256) void scatter_kernel(const int* __restrict__ src,
                                                      const int* __restrict__ dst,
                                                      int* __restrict__ woff,
                                                      int* __restrict__ src_sorted, int n_edges) {
    int e = blockIdx.x * 256 + threadIdx.x;
    if (e < n_edges) {
        int p = atomicAdd(&woff[dst[e]], 1);
        src_sorted[p] = src[e];
    }
}

// ---------------- aggregation ----------------
// Half-wave (32 lanes x float4 = full 128-col row) per node: no cross-lane
// reduction needed. 4-deep unrolled gather -> 4 loads in flight per lane.

__global__ __launch_bounds__(256) void agg_kernel(const float* __restrict__ xin,
                                                  const int* __restrict__ row_ptr,
                                                  const int* __restrict__ src_sorted,
                                                  float* __restrict__ agg, int n_nodes) {
    int node = blockIdx.x * 8 + (threadIdx.x >> 5);
    if (node >= n_nodes) return;
    int c = threadIdx.x & 31;  // float4 column group
    int jb = row_ptr[node], je = row_ptr[node + 1];
    const float4* xp = (const float4*)xin;  // row stride = 32 float4

    float4 a0 = make_float4(0.f, 0.f, 0.f, 0.f);
    float4 a1 = make_float4(0.f, 0.f, 0.f, 0.f);
    float4 a2 = make_float4(0.f, 0.f, 0.f, 0.f);
    float4 a3 = make_float4(0.f, 0.f, 0.f, 0.f);
    int j = jb;
    for (; j + 3 < je; j += 4) {
        int s0 = src_sorted[j];
        int s1 = src_sorted[j + 1];
        int s2 = src_sorted[j + 2];
        int s3 = src_sorted[j + 3];
        float4 v0 = xp[s0 * 32 + c];
        float4 v1 = xp[s1 * 32 + c];
        float4 v2 = xp[s2 * 32 + c];
        float4 v3 = xp[s3 * 32 + c];
        a0.x += v0.x; a0.y += v0.y; a0.z += v0.z; a0.w += v0.w;
        a1.x += v1.x; a1.y += v1.y; a1.z += v1.z; a1.w += v1.w;
        a2.x += v2.x; a2.y += v2.y; a2.z += v2.z; a2.w += v2.w;
        a3.x += v3.x; a3.y += v3.y; a3.z += v3.z; a3.w += v3.w;
    }
    for (; j < je; ++j) {
        int s0 = src_sorted[j];
        float4 v0 = xp[s0 * 32 + c];
        a0.x += v0.x; a0.y += v0.y; a0.z += v0.z; a0.w += v0.w;
    }
    a0.x += a1.x + a2.x + a3.x;
    a0.y += a1.y + a2.y + a3.y;
    a0.z += a1.z + a2.z + a3.z;
    a0.w += a1.w + a2.w + a3.w;
    ((float4*)agg)[node * 32 + c] = a0;
}

// ---------------- fused GEMM (M x 128 @ 128 x 128) + bias + L2-normalize + ReLU ----------------
// Wave = 64 nodes x 32 cols. Column base c0 is wave-uniform (readfirstlane),
// so W and bias reads are uniform-addressed -> scalar loads (SGPR path, K$),
// leaving the vector pipe pure FMA. acc[32] per lane. Cross-wave row-norm
// via a 1 KB LDS exchange.

__global__ __launch_bounds__(256) void gemm_norm_kernel(const float* __restrict__ A,
                                                        const float* __restrict__ W,
                                                        const float* __restrict__ bias,
                                                        float* __restrict__ out, int M) {
    __shared__ float ss_lds[4][64];
    int lane = threadIdx.x & 63;
    int wv = threadIdx.x >> 6;
    int c0 = __builtin_amdgcn_readfirstlane(wv * 32);  // wave-uniform col base
    int node = blockIdx.x * 64 + lane;
    int nclamp = node < M ? node : M - 1;
    const float* Arow = A + (size_t)nclamp * NFEAT;

    float acc[32];
#pragma unroll
    for (int i = 0; i < 32; ++i) acc[i] = 0.f;

    for (int k = 0; k < NFEAT; k += 4) {
        float4 a = *(const float4*)(Arow + k);
#pragma unroll
        for (int kk = 0; kk < 4; ++kk) {
            float av = (&a.x)[kk];
            const float* Wr = W + (k + kk) * NFEAT + c0;  // uniform address
#pragma unroll
            for (int c = 0; c < 32; ++c) acc[c] += av * Wr[c];
        }
    }

    float ss = 0.f;
#pragma unroll
    for (int c = 0; c < 32; ++c) {
        acc[c] += bias[c0 + c];  // uniform -> s_load
        ss += acc[c] * acc[c];
    }
    ss_lds[wv][lane] = ss;
    __syncthreads();
    float tot = ss_lds[0][lane] + ss_lds[1][lane] + ss_lds[2][lane] + ss_lds[3][lane];
    float inv = 1.0f / fmaxf(sqrtf(tot), 1e-12f);

    if (node < M) {
        float4* o = (float4*)(out + (size_t)node * NFEAT + c0);
#pragma unroll
        for (int c = 0; c < 32; c += 4) {
            float4 v;
            v.x = fmaxf(acc[c + 0] * inv, 0.f);
            v.y = fmaxf(acc[c + 1] * inv, 0.f);
            v.z = fmaxf(acc[c + 2] * inv, 0.f);
            v.w = fmaxf(acc[c + 3] * inv, 0.f);
            o[c >> 2] = v;
        }
    }
}

// ---------------- classifier: logits = x4 @ Wl + bl; softmax ----------------
// Thread = 1 node, acc[40] in VGPRs. Wl/bl addresses are fully uniform ->
// scalar loads; per-thread softmax, float4 stores. No LDS at all.

__global__ __launch_bounds__(256) void classifier_kernel(const float* __restrict__ x4,
                                                         const float* __restrict__ Wl,
                                                         const float* __restrict__ bl,
                                                         float* __restrict__ logits,
                                                         float* __restrict__ probs, int n_nodes) {
    int node = blockIdx.x * 256 + threadIdx.x;
    int nc = node < n_nodes ? node : n_nodes - 1;
    const float* row = x4 + (size_t)nc * NFEAT;

    float acc[NCLASS];
#pragma unroll
    for (int c = 0; c < NCLASS; ++c) acc[c] = bl[c];  // uniform -> s_load

    for (int k = 0; k < NFEAT; k += 4) {
        float4 a = *(const float4*)(row + k);
#pragma unroll
        for (int kk = 0; kk < 4; ++kk) {
            float av = (&a.x)[kk];
            const float* Wr = Wl + (k + kk) * NCLASS;  // uniform address
#pragma unroll
            for (int c = 0; c < NCLASS; ++c) acc[c] += av * Wr[c];
        }
    }

    float m = acc[0];
#pragma unroll
    for (int c = 1; c < NCLASS; ++c) m = fmaxf(m, acc[c]);
    float ex[NCLASS];
    float sum = 0.f;
#pragma unroll
    for (int c = 0; c < NCLASS; ++c) {
        ex[c] = __expf(acc[c] - m);
        sum += ex[c];
    }
    float is = 1.0f / sum;

    if (node < n_nodes) {
        float4* lo = (float4*)(logits + (size_t)node * NCLASS);
        float4* po = (float4*)(probs + (size_t)node * NCLASS);
#pragma unroll
        for (int c = 0; c < NCLASS; c += 4) {
            float4 lv, pv;
            lv.x = acc[c + 0]; lv.y = acc[c + 1]; lv.z = acc[c + 2]; lv.w = acc[c + 3];
            pv.x = ex[c + 0] * is; pv.y = ex[c + 1] * is; pv.z = ex[c + 2] * is; pv.w = ex[c + 3] * is;
            lo[c >> 2] = lv;
            po[c >> 2] = pv;
        }
    }
}

// ---------------- launch ----------------

extern "C" void kernel_launch(void* const* d_in, const int* in_sizes, int n_in,
                              void* d_out, int out_size, void* d_ws, size_t ws_size,
                              hipStream_t stream) {
    const float* x  = (const float*)d_in[0];
    const int*   ei = (const int*)d_in[1];
    const float* W1 = (const float*)d_in[2];
    const float* b1 = (const float*)d_in[3];
    const float* W2 = (const float*)d_in[4];
    const float* b2 = (const float*)d_in[5];
    const float* W3 = (const float*)d_in[6];
    const float* b3 = (const float*)d_in[7];
    const float* W4 = (const float*)d_in[8];
    const float* b4 = (const float*)d_in[9];
    const float* Wl = (const float*)d_in[10];
    const float* bl = (const float*)d_in[11];

    const int n_nodes = in_sizes[0] / NFEAT;  // 50000
    const int n_edges = in_sizes[1] / 2;      // 640000
    const int* src = ei;
    const int* dst = ei + n_edges;

    float* out    = (float*)d_out;
    float* logits = out;
    float* probs  = out + (size_t)n_nodes * NCLASS;
    float* x4     = out + 2 * (size_t)n_nodes * NCLASS;  // also the layer ping buffer

    // workspace layout
    char* ws = (char*)d_ws;
    size_t off = 0;
    auto wsalloc = [&](size_t bytes) -> void* {
        void* p = ws + off;
        off += (bytes + 255) & ~(size_t)255;
        return p;
    };
    float* agg        = (float*)wsalloc((size_t)n_nodes * NFEAT * sizeof(float));
    int*   row_ptr    = (int*)wsalloc(((size_t)n_nodes + 1) * sizeof(int));
    int*   woff       = (int*)wsalloc((size_t)n_nodes * sizeof(int));
    int*   cnt        = (int*)wsalloc((size_t)n_nodes * sizeof(int));
    int*   src_sorted = (int*)wsalloc((size_t)n_edges * sizeof(int));
    int    nb         = (n_nodes + 255) / 256;
    int*   bsums      = (int*)wsalloc(((size_t)nb + 1) * sizeof(int));

    // CSR build (dst-bucketed)
    hipMemsetAsync(cnt, 0, (size_t)n_nodes * sizeof(int), stream);
    int eb = (n_edges + 255) / 256;
    hist_kernel<<<eb, 256, 0, stream>>>(dst, cnt, n_edges);
    scan1_kernel<<<nb, 256, 0, stream>>>(cnt, row_ptr /*excl temp*/, bsums, n_nodes);
    scan2_kernel<<<1, 256, 0, stream>>>(bsums, nb);
    scan3_kernel<<<nb, 256, 0, stream>>>(row_ptr, bsums, row_ptr, woff, n_nodes, nb);
    scatter_kernel<<<eb, 256, 0, stream>>>(src, dst, woff, src_sorted, n_edges);

    int ab = (n_nodes + 7) / 8;    // agg: 8 nodes / block
    int gb = (n_nodes + 63) / 64;  // gemm: 64 nodes / block
    int cb = (n_nodes + 255) / 256;

    // layer 1 (agg-first reordering: segment_sum commutes with @W)
    agg_kernel<<<ab, 256, 0, stream>>>(x, row_ptr, src_sorted, agg, n_nodes);
    gemm_norm_kernel<<<gb, 256, 0, stream>>>(agg, W1, b1, x4, n_nodes);
    // layer 2
    agg_kernel<<<ab, 256, 0, stream>>>(x4, row_ptr, src_sorted, agg, n_nodes);
    gemm_norm_kernel<<<gb, 256, 0, stream>>>(agg, W2, b2, x4, n_nodes);
    // layer 3
    agg_kernel<<<ab, 256, 0, stream>>>(x4, row_ptr, src_sorted, agg, n_nodes);
    gemm_norm_kernel<<<gb, 256, 0, stream>>>(agg, W3, b3, x4, n_nodes);
    // layer 4 (writes x4 output region directly)
    agg_kernel<<<ab, 256, 0, stream>>>(x4, row_ptr, src_sorted, agg, n_nodes);
    gemm_norm_kernel<<<gb, 256, 0, stream>>>(agg, W4, b4, x4, n_nodes);

    // classifier + softmax
    classifier_kernel<<<cb, 256, 0, stream>>>(x4, Wl, bl, logits, probs, n_nodes);
}

// Round 4
// 505.836 us; speedup vs baseline: 1.4383x; 1.0227x over previous
//
#include <hip/hip_runtime.h>
#include <hip/hip_bf16.h>
#include <math.h>

#define NFEAT 128
#define NCLASS 40
#define ASTRIDE 129  // 64x129 f32 LDS tile: (lane*129+k)%32 -> 2 lanes/bank (free)

// ---------------- CSR build ----------------

__global__ __launch_bounds__(256) void hist_kernel(const int* __restrict__ dst,
                                                   int* __restrict__ counts, int n_edges) {
    int i = blockIdx.x * 256 + threadIdx.x;
    int n4 = n_edges >> 2;
    if (i < n4) {
        int4 d = ((const int4*)dst)[i];
        atomicAdd(&counts[d.x], 1);
        atomicAdd(&counts[d.y], 1);
        atomicAdd(&counts[d.z], 1);
        atomicAdd(&counts[d.w], 1);
    }
    if (i == 0) {
        for (int e = n4 << 2; e < n_edges; ++e) atomicAdd(&counts[dst[e]], 1);
    }
}

// Phase 1: per-block (256-wide) exclusive scan of counts; block totals out.
__global__ __launch_bounds__(256) void scan1_kernel(const int* __restrict__ cnt,
                                                    int* __restrict__ excl,
                                                    int* __restrict__ bsums, int n) {
    __shared__ int sd[256];
    int t = threadIdx.x;
    int i = blockIdx.x * 256 + t;
    int v = (i < n) ? cnt[i] : 0;
    sd[t] = v;
    __syncthreads();
#pragma unroll
    for (int off = 1; off < 256; off <<= 1) {
        int tmp = (t >= off) ? sd[t - off] : 0;
        __syncthreads();
        sd[t] += tmp;
        __syncthreads();
    }
    if (i < n) excl[i] = sd[t] - v;
    if (t == 255) bsums[blockIdx.x] = sd[255];
}

// Phase 2: single block scans the (<=256) block sums in-place (exclusive).
__global__ __launch_bounds__(256) void scan2_kernel(int* __restrict__ bsums, int nb) {
    __shared__ int sd[256];
    int t = threadIdx.x;
    int v = (t < nb) ? bsums[t] : 0;
    sd[t] = v;
    __syncthreads();
#pragma unroll
    for (int off = 1; off < 256; off <<= 1) {
        int tmp = (t >= off) ? sd[t - off] : 0;
        __syncthreads();
        sd[t] += tmp;
        __syncthreads();
    }
    if (t < nb) bsums[t] = sd[t] - v;
    if (t == 255) bsums[nb] = sd[255];
}

// Phase 3: add block offsets -> final row_ptr and woff (scatter cursor).
__global__ __launch_bounds__(256) void scan3_kernel(const int* __restrict__ excl,
                                                    const int* __restrict__ bsums,
                                                    int* __restrict__ row_ptr,
                                                    int* __restrict__ woff, int n, int nb) {
    int i = blockIdx.x * 256 + threadIdx.x;
    if (i < n) {
        int v = excl[i] + bsums[blockIdx.x];
        row_ptr[i] = v;
        woff[i] = v;
    }
    if (i == 0) row_ptr[n] = bsums[nb];
}

__global__ __launch_bounds__(256) void scatter_kernel(const int* __restrict__ src,
                                                      const int* __restrict__ dst,
                                                      int* __restrict__ woff,
                                                      int* __restrict__ src_sorted, int n_edges) {
    int i = blockIdx.x * 256 + threadIdx.x;
    int n4 = n_edges >> 2;
    if (i < n4) {
        int4 d = ((const int4*)dst)[i];
        int4 s = ((const int4*)src)[i];
        int p0 = atomicAdd(&woff[d.x], 1);
        int p1 = atomicAdd(&woff[d.y], 1);
        int p2 = atomicAdd(&woff[d.z], 1);
        int p3 = atomicAdd(&woff[d.w], 1);
        src_sorted[p0] = s.x;
        src_sorted[p1] = s.y;
        src_sorted[p2] = s.z;
        src_sorted[p3] = s.w;
    }
    if (i == 0) {
        for (int e = n4 << 2; e < n_edges; ++e) {
            int p = atomicAdd(&woff[dst[e]], 1);
            src_sorted[p] = src[e];
        }
    }
}

// ---------------- fused layer: agg (gather) + GEMM + bias + L2-normalize + ReLU ----------------
// Block = 64 nodes, 256 threads.
// Phase 1: 8 half-waves; half-wave gathers 8 node-rows (float4/lane, 4-deep
//          pipeline) into LDS As[64][129] via b32 stores.
// Phase 2: lane = node (reads As[lane][k], 2 lanes/bank = conflict-free);
//          wave = 32-col slice, W/bias via wave-uniform scalar loads;
//          cross-wave row-norm via 1 KB LDS; fused bias+normalize+ReLU store.

__global__ __launch_bounds__(256) void layer_kernel(const float* __restrict__ xin,
                                                    const int* __restrict__ row_ptr,
                                                    const int* __restrict__ src_sorted,
                                                    const float* __restrict__ W,
                                                    const float* __restrict__ bias,
                                                    float* __restrict__ out, int M) {
    __shared__ float As[64 * ASTRIDE];  // ~33 KB
    __shared__ float ss_lds[4][64];
    int tid = threadIdx.x;
    int base = blockIdx.x * 64;

    // ---- phase 1: gather ----
    {
        int hw = tid >> 5;  // half-wave id 0..7
        int c = tid & 31;   // float4 column group
        const float4* xp = (const float4*)xin;  // row stride 32 float4
#pragma unroll
        for (int i = 0; i < 8; ++i) {
            int slot = hw * 8 + i;
            int node = base + slot;
            int nc = node < M ? node : M - 1;
            int jb = row_ptr[nc], je = row_ptr[nc + 1];
            if (node >= M) je = jb;  // OOB slots: zeros
            float4 a0 = make_float4(0.f, 0.f, 0.f, 0.f);
            float4 a1 = make_float4(0.f, 0.f, 0.f, 0.f);
            float4 a2 = make_float4(0.f, 0.f, 0.f, 0.f);
            float4 a3 = make_float4(0.f, 0.f, 0.f, 0.f);
            int j = jb;
            for (; j + 3 < je; j += 4) {
                int s0 = src_sorted[j];
                int s1 = src_sorted[j + 1];
                int s2 = src_sorted[j + 2];
                int s3 = src_sorted[j + 3];
                float4 v0 = xp[s0 * 32 + c];
                float4 v1 = xp[s1 * 32 + c];
                float4 v2 = xp[s2 * 32 + c];
                float4 v3 = xp[s3 * 32 + c];
                a0.x += v0.x; a0.y += v0.y; a0.z += v0.z; a0.w += v0.w;
                a1.x += v1.x; a1.y += v1.y; a1.z += v1.z; a1.w += v1.w;
                a2.x += v2.x; a2.y += v2.y; a2.z += v2.z; a2.w += v2.w;
                a3.x += v3.x; a3.y += v3.y; a3.z += v3.z; a3.w += v3.w;
            }
            for (; j < je; ++j) {
                int s0 = src_sorted[j];
                float4 v0 = xp[s0 * 32 + c];
                a0.x += v0.x; a0.y += v0.y; a0.z += v0.z; a0.w += v0.w;
            }
            a0.x += a1.x + a2.x + a3.x;
            a0.y += a1.y + a2.y + a3.y;
            a0.z += a1.z + a2.z + a3.z;
            a0.w += a1.w + a2.w + a3.w;
            int w0 = slot * ASTRIDE + 4 * c;
            As[w0 + 0] = a0.x;
            As[w0 + 1] = a0.y;
            As[w0 + 2] = a0.z;
            As[w0 + 3] = a0.w;
        }
    }
    __syncthreads();

    // ---- phase 2: GEMM + bias + norm + relu ----
    int lane = tid & 63;
    int wv = tid >> 6;
    int c0 = __builtin_amdgcn_readfirstlane(wv * 32);  // wave-uniform col base
    int node = base + lane;
    const float* Arow = &As[lane * ASTRIDE];

    float acc[32];
#pragma unroll
    for (int i = 0; i < 32; ++i) acc[i] = 0.f;

    for (int k = 0; k < NFEAT; k += 4) {
        float a0 = Arow[k + 0];
        float a1 = Arow[k + 1];
        float a2 = Arow[k + 2];
        float a3 = Arow[k + 3];
        const float* Wr0 = W + (k + 0) * NFEAT + c0;  // uniform -> s_load
        const float* Wr1 = W + (k + 1) * NFEAT + c0;
        const float* Wr2 = W + (k + 2) * NFEAT + c0;
        const float* Wr3 = W + (k + 3) * NFEAT + c0;
#pragma unroll
        for (int c = 0; c < 32; ++c) {
            acc[c] += a0 * Wr0[c];
            acc[c] += a1 * Wr1[c];
            acc[c] += a2 * Wr2[c];
            acc[c] += a3 * Wr3[c];
        }
    }

    float ss = 0.f;
#pragma unroll
    for (int c = 0; c < 32; ++c) {
        acc[c] += bias[c0 + c];
        ss += acc[c] * acc[c];
    }
    ss_lds[wv][lane] = ss;
    __syncthreads();
    float tot = ss_lds[0][lane] + ss_lds[1][lane] + ss_lds[2][lane] + ss_lds[3][lane];
    float inv = 1.0f / fmaxf(sqrtf(tot), 1e-12f);

    if (node < M) {
        float4* o = (float4*)(out + (size_t)node * NFEAT + c0);
#pragma unroll
        for (int c = 0; c < 32; c += 4) {
            float4 v;
            v.x = fmaxf(acc[c + 0] * inv, 0.f);
            v.y = fmaxf(acc[c + 1] * inv, 0.f);
            v.z = fmaxf(acc[c + 2] * inv, 0.f);
            v.w = fmaxf(acc[c + 3] * inv, 0.f);
            o[c >> 2] = v;
        }
    }
}

// ---------------- classifier: logits = x4 @ Wl + bl; softmax ----------------

__global__ __launch_bounds__(256) void classifier_kernel(const float* __restrict__ x4,
                                                         const float* __restrict__ Wl,
                                                         const float* __restrict__ bl,
                                                         float* __restrict__ logits,
                                                         float* __restrict__ probs, int n_nodes) {
    int node = blockIdx.x * 256 + threadIdx.x;
    int nc = node < n_nodes ? node : n_nodes - 1;
    const float* row = x4 + (size_t)nc * NFEAT;

    float acc[NCLASS];
#pragma unroll
    for (int c = 0; c < NCLASS; ++c) acc[c] = bl[c];  // uniform -> s_load

    for (int k = 0; k < NFEAT; k += 4) {
        float4 a = *(const float4*)(row + k);
#pragma unroll
        for (int kk = 0; kk < 4; ++kk) {
            float av = (&a.x)[kk];
            const float* Wr = Wl + (k + kk) * NCLASS;  // uniform address
#pragma unroll
            for (int c = 0; c < NCLASS; ++c) acc[c] += av * Wr[c];
        }
    }

    float m = acc[0];
#pragma unroll
    for (int c = 1; c < NCLASS; ++c) m = fmaxf(m, acc[c]);
    float ex[NCLASS];
    float sum = 0.f;
#pragma unroll
    for (int c = 0; c < NCLASS; ++c) {
        ex[c] = __expf(acc[c] - m);
        sum += ex[c];
    }
    float is = 1.0f / sum;

    if (node < n_nodes) {
        float4* lo = (float4*)(logits + (size_t)node * NCLASS);
        float4* po = (float4*)(probs + (size_t)node * NCLASS);
#pragma unroll
        for (int c = 0; c < NCLASS; c += 4) {
            float4 lv, pv;
            lv.x = acc[c + 0]; lv.y = acc[c + 1]; lv.z = acc[c + 2]; lv.w = acc[c + 3];
            pv.x = ex[c + 0] * is; pv.y = ex[c + 1] * is; pv.z = ex[c + 2] * is; pv.w = ex[c + 3] * is;
            lo[c >> 2] = lv;
            po[c >> 2] = pv;
        }
    }
}

// ---------------- launch ----------------

extern "C" void kernel_launch(void* const* d_in, const int* in_sizes, int n_in,
                              void* d_out, int out_size, void* d_ws, size_t ws_size,
                              hipStream_t stream) {
    const float* x  = (const float*)d_in[0];
    const int*   ei = (const int*)d_in[1];
    const float* W1 = (const float*)d_in[2];
    const float* b1 = (const float*)d_in[3];
    const float* W2 = (const float*)d_in[4];
    const float* b2 = (const float*)d_in[5];
    const float* W3 = (const float*)d_in[6];
    const float* b3 = (const float*)d_in[7];
    const float* W4 = (const float*)d_in[8];
    const float* b4 = (const float*)d_in[9];
    const float* Wl = (const float*)d_in[10];
    const float* bl = (const float*)d_in[11];

    const int n_nodes = in_sizes[0] / NFEAT;  // 50000
    const int n_edges = in_sizes[1] / 2;      // 640000
    const int* src = ei;
    const int* dst = ei + n_edges;

    float* out    = (float*)d_out;
    float* logits = out;
    float* probs  = out + (size_t)n_nodes * NCLASS;
    float* x4     = out + 2 * (size_t)n_nodes * NCLASS;  // layer ping buffer

    // workspace layout
    char* ws = (char*)d_ws;
    size_t off = 0;
    auto wsalloc = [&](size_t bytes) -> void* {
        void* p = ws + off;
        off += (bytes + 255) & ~(size_t)255;
        return p;
    };
    float* xbuf       = (float*)wsalloc((size_t)n_nodes * NFEAT * sizeof(float));  // layer pong
    int*   row_ptr    = (int*)wsalloc(((size_t)n_nodes + 1) * sizeof(int));
    int*   woff       = (int*)wsalloc((size_t)n_nodes * sizeof(int));
    int*   cnt        = (int*)wsalloc((size_t)n_nodes * sizeof(int));
    int*   src_sorted = (int*)wsalloc((size_t)n_edges * sizeof(int));
    int    nb         = (n_nodes + 255) / 256;
    int*   bsums      = (int*)wsalloc(((size_t)nb + 1) * sizeof(int));

    // CSR build (dst-bucketed)
    hipMemsetAsync(cnt, 0, (size_t)n_nodes * sizeof(int), stream);
    int e4b = ((n_edges >> 2) + 255) / 256;
    hist_kernel<<<e4b, 256, 0, stream>>>(dst, cnt, n_edges);
    scan1_kernel<<<nb, 256, 0, stream>>>(cnt, row_ptr /*excl temp*/, bsums, n_nodes);
    scan2_kernel<<<1, 256, 0, stream>>>(bsums, nb);
    scan3_kernel<<<nb, 256, 0, stream>>>(row_ptr, bsums, row_ptr, woff, n_nodes, nb);
    scatter_kernel<<<e4b, 256, 0, stream>>>(src, dst, woff, src_sorted, n_edges);

    int gb = (n_nodes + 63) / 64;
    int cb = (n_nodes + 255) / 256;

    // fused layers (agg-first reordering: segment_sum commutes with @W)
    layer_kernel<<<gb, 256, 0, stream>>>(x,    row_ptr, src_sorted, W1, b1, xbuf, n_nodes);
    layer_kernel<<<gb, 256, 0, stream>>>(xbuf, row_ptr, src_sorted, W2, b2, x4,   n_nodes);
    layer_kernel<<<gb, 256, 0, stream>>>(x4,   row_ptr, src_sorted, W3, b3, xbuf, n_nodes);
    layer_kernel<<<gb, 256, 0, stream>>>(xbuf, row_ptr, src_sorted, W4, b4, x4,   n_nodes);

    // classifier + softmax
    classifier_kernel<<<cb, 256, 0, stream>>>(x4, Wl, bl, logits, probs, n_nodes);
}